// Round 1
// baseline (3979.852 us; speedup 1.0000x reference)
//
#include <hip/hip_runtime.h>

#define DD 128

__device__ __forceinline__ float tanh_fast(float x) {
  float e = __expf(2.0f * x);
  return 1.0f - 2.0f / (e + 1.0f);
}

// f32 -> bf16 round-to-nearest-even (no NaN handling needed here)
__device__ __forceinline__ unsigned short f2bf(float f) {
  unsigned u = __float_as_uint(f);
  u += 0x7FFFu + ((u >> 16) & 1u);
  return (unsigned short)(u >> 16);
}

__device__ __forceinline__ void fma4(float (&a)[4], float x, const float4 w) {
  a[0] = fmaf(x, w.x, a[0]);
  a[1] = fmaf(x, w.y, a[1]);
  a[2] = fmaf(x, w.z, a[2]);
  a[3] = fmaf(x, w.w, a[3]);
}

// K1: P[v] = emb[v] @ W_attn[0:128,:] + b_attn   (the r/dst part, bias folded)
//     Q[v] = emb[v] @ W_attn[128:256,:]          (the h/src part)
// stored as bf16. 64 nodes/block, 256 threads, X tile in LDS.
extern "C" __global__ __launch_bounds__(256) void k_pq(
    const float* __restrict__ emb, const float* __restrict__ Wattn,
    const float* __restrict__ battn,
    unsigned short* __restrict__ P, unsigned short* __restrict__ Q, int n) {
  __shared__ float X[64][DD];
  const int tid = threadIdx.x;
  const int v0 = blockIdx.x * 64;
  const float4* emb4 = (const float4*)emb;
#pragma unroll
  for (int i = 0; i < 8; ++i) {
    int idx = tid + i * 256;      // 0..2047 = 64 rows x 32 float4
    int r = idx >> 5, c4 = idx & 31;
    int v = v0 + r;
    float4 val = make_float4(0.f, 0.f, 0.f, 0.f);
    if (v < n) val = emb4[(size_t)v * 32 + c4];
    *(float4*)&X[r][c4 * 4] = val;
  }
  __syncthreads();
  const int c = (tid & 31) * 4;
  const int r0 = (tid >> 5) * 8;
  float aP[8][4] = {};
  float aQ[8][4] = {};
  for (int k = 0; k < DD; ++k) {
    float4 wt = *(const float4*)&Wattn[k * DD + c];
    float4 wb = *(const float4*)&Wattn[(DD + k) * DD + c];
#pragma unroll
    for (int r = 0; r < 8; ++r) {
      float x = X[r0 + r][k];
      fma4(aP[r], x, wt);
      fma4(aQ[r], x, wb);
    }
  }
  float4 bb = *(const float4*)&battn[c];
#pragma unroll
  for (int r = 0; r < 8; ++r) {
    int v = v0 + r0 + r;
    if (v < n) {
      ushort4 sp, sq;
      sp.x = f2bf(aP[r][0] + bb.x);
      sp.y = f2bf(aP[r][1] + bb.y);
      sp.z = f2bf(aP[r][2] + bb.z);
      sp.w = f2bf(aP[r][3] + bb.w);
      sq.x = f2bf(aQ[r][0]);
      sq.y = f2bf(aQ[r][1]);
      sq.z = f2bf(aQ[r][2]);
      sq.w = f2bf(aQ[r][3]);
      *(ushort4*)&P[(size_t)v * DD + c] = sp;
      *(ushort4*)&Q[(size_t)v * DD + c] = sq;
    }
  }
}

// K2: per ER edge: s = tanh(P[dst]+Q[src]) . w0 + w0_b ; e_ij[e]=s ;
// atomicMax(seg_max[src], max(s,0)) via int bits (nonneg floats int-ordered).
// 16 lanes per edge, 8 elems per lane.
extern "C" __global__ __launch_bounds__(256) void k_eij(
    const unsigned short* __restrict__ P, const unsigned short* __restrict__ Q,
    const int* __restrict__ src, const int* __restrict__ dstp,
    const float* __restrict__ w0w, const float* __restrict__ w0b,
    float* __restrict__ e_ij, int* __restrict__ mmax, int nE) {
  int t = blockIdx.x * 256 + threadIdx.x;
  int e = t >> 4;
  if (e >= nE) return;
  int lane = t & 15;
  int s = src[e], d = dstp[e];
  uint4 pv = *(const uint4*)(P + (size_t)d * DD + lane * 8);
  uint4 qv = *(const uint4*)(Q + (size_t)s * DD + lane * 8);
  float4 wa = *(const float4*)&w0w[lane * 8];
  float4 wbv = *(const float4*)&w0w[lane * 8 + 4];
  unsigned pw[4] = {pv.x, pv.y, pv.z, pv.w};
  unsigned qw[4] = {qv.x, qv.y, qv.z, qv.w};
  float wv[8] = {wa.x, wa.y, wa.z, wa.w, wbv.x, wbv.y, wbv.z, wbv.w};
  float acc = 0.f;
#pragma unroll
  for (int j = 0; j < 8; ++j) {
    unsigned up = (j & 1) ? (pw[j >> 1] & 0xFFFF0000u) : (pw[j >> 1] << 16);
    unsigned uq = (j & 1) ? (qw[j >> 1] & 0xFFFF0000u) : (qw[j >> 1] << 16);
    float x = __uint_as_float(up) + __uint_as_float(uq);
    acc = fmaf(tanh_fast(x), wv[j], acc);
  }
  acc += __shfl_xor(acc, 8);
  acc += __shfl_xor(acc, 4);
  acc += __shfl_xor(acc, 2);
  acc += __shfl_xor(acc, 1);
  if (lane == 0) {
    float sv = acc + w0b[0];
    e_ij[e] = sv;
    atomicMax(&mmax[s], __float_as_int(fmaxf(sv, 0.0f)));
  }
}

// K3: per ER edge: ev = exp(e_ij - m[src]); ssum[src]+=ev; U[src] += ev*emb[dst].
// Division by (ssum+1e-9) deferred to K5 (per-segment constant).
extern "C" __global__ __launch_bounds__(256) void k_agg(
    const float* __restrict__ emb, const int* __restrict__ src,
    const int* __restrict__ dstp, const float* __restrict__ e_ij,
    const int* __restrict__ mmax, float* __restrict__ ssum,
    float* __restrict__ U, int nE) {
  int t = blockIdx.x * 256 + threadIdx.x;
  int e = t >> 4;
  if (e >= nE) return;
  int lane = t & 15;
  int s = src[e], d = dstp[e];
  float ev = __expf(e_ij[e] - __int_as_float(mmax[s]));
  if (lane == 0) unsafeAtomicAdd(&ssum[s], ev);
  const float4 a = *(const float4*)&emb[(size_t)d * DD + lane * 8];
  const float4 b = *(const float4*)&emb[(size_t)d * DD + lane * 8 + 4];
  float* Up = U + (size_t)s * DD + lane * 8;
  unsafeAtomicAdd(Up + 0, ev * a.x);
  unsafeAtomicAdd(Up + 1, ev * a.y);
  unsafeAtomicAdd(Up + 2, ev * a.z);
  unsafeAtomicAdd(Up + 3, ev * a.w);
  unsafeAtomicAdd(Up + 4, ev * b.x);
  unsafeAtomicAdd(Up + 5, ev * b.y);
  unsafeAtomicAdd(Up + 6, ev * b.z);
  unsafeAtomicAdd(Up + 7, ev * b.w);
}

// K4: weighted out-degree over EE edges (gather and scatter are BOTH ee_src).
extern "C" __global__ __launch_bounds__(256) void k_deg(
    const int* __restrict__ src, const float* __restrict__ wgt,
    float* __restrict__ g, int nE) {
  int e = blockIdx.x * 256 + threadIdx.x;
  if (e < nE) unsafeAtomicAdd(&g[src[e]], wgt[e]);
}

// K5: out = tanh( emb@W_self + b_self + M@W_neigh + (t+g)*b_neigh )
// where M = U/(ssum+1e-9) + g*emb, t = ssum/(ssum+1e-9).
// 32 nodes/block, two fp32 X tiles in LDS.
extern "C" __global__ __launch_bounds__(256) void k_out(
    const float* __restrict__ emb, const float* __restrict__ U,
    const float* __restrict__ ssum, const float* __restrict__ g,
    const float* __restrict__ Wself, const float* __restrict__ bself,
    const float* __restrict__ Wneigh, const float* __restrict__ bneigh,
    float* __restrict__ out, int n) {
  __shared__ float X1[32][DD];
  __shared__ float X2[32][DD];
  const int tid = threadIdx.x;
  const int v0 = blockIdx.x * 32;
  const float4* emb4 = (const float4*)emb;
  const float4* U4 = (const float4*)U;
#pragma unroll
  for (int i = 0; i < 4; ++i) {
    int idx = tid + i * 256;      // 0..1023 = 32 rows x 32 float4
    int r = idx >> 5, c4 = idx & 31;
    int v = v0 + r;
    float4 x = make_float4(0.f, 0.f, 0.f, 0.f);
    float4 m = x;
    if (v < n) {
      x = emb4[(size_t)v * 32 + c4];
      float4 u = U4[(size_t)v * 32 + c4];
      float sv = ssum[v];
      float gv = g[v];
      float inv = 1.0f / (sv + 1e-9f);
      m.x = fmaf(gv, x.x, u.x * inv);
      m.y = fmaf(gv, x.y, u.y * inv);
      m.z = fmaf(gv, x.z, u.z * inv);
      m.w = fmaf(gv, x.w, u.w * inv);
    }
    *(float4*)&X1[r][c4 * 4] = x;
    *(float4*)&X2[r][c4 * 4] = m;
  }
  __syncthreads();
  const int c = (tid & 31) * 4;
  const int r0 = (tid >> 5) * 4;
  float acc[4][4] = {};
  for (int k = 0; k < DD; ++k) {
    float4 ws = *(const float4*)&Wself[k * DD + c];
    float4 wn = *(const float4*)&Wneigh[k * DD + c];
#pragma unroll
    for (int r = 0; r < 4; ++r) {
      float x1 = X1[r0 + r][k];
      float x2 = X2[r0 + r][k];
      fma4(acc[r], x1, ws);
      fma4(acc[r], x2, wn);
    }
  }
  float4 bs = *(const float4*)&bself[c];
  float4 bn = *(const float4*)&bneigh[c];
#pragma unroll
  for (int r = 0; r < 4; ++r) {
    int v = v0 + r0 + r;
    if (v < n) {
      float sv = ssum[v];
      float gv = g[v];
      float tg = sv / (sv + 1e-9f) + gv;
      float4 y;
      y.x = tanh_fast(acc[r][0] + bs.x + tg * bn.x);
      y.y = tanh_fast(acc[r][1] + bs.y + tg * bn.y);
      y.z = tanh_fast(acc[r][2] + bs.z + tg * bn.z);
      y.w = tanh_fast(acc[r][3] + bs.w + tg * bn.w);
      *(float4*)&out[(size_t)v * DD + c] = y;
    }
  }
}

extern "C" void kernel_launch(void* const* d_in, const int* in_sizes, int n_in,
                              void* d_out, int out_size, void* d_ws, size_t ws_size,
                              hipStream_t stream) {
  const float* emb = (const float*)d_in[0];
  const int* er_src = (const int*)d_in[1];
  const int* er_dst = (const int*)d_in[2];
  const int* ee_src = (const int*)d_in[3];
  // d_in[4] = ee_dst: unused by the reference computation
  const float* ee_w = (const float*)d_in[5];
  const float* Wattn = (const float*)d_in[6];
  const float* battn = (const float*)d_in[7];
  const float* w0w = (const float*)d_in[8];
  const float* w0b = (const float*)d_in[9];
  const float* Wself = (const float*)d_in[10];
  const float* bself = (const float*)d_in[11];
  const float* Wneigh = (const float*)d_in[12];
  const float* bneigh = (const float*)d_in[13];
  const int n = in_sizes[0] / DD;
  const int nER = in_sizes[1];
  const int nEE = in_sizes[3];

  // workspace layout:
  // [0, n*128*4)            : P,Q (bf16, n*128 each) -- later reused as U (f32, n*128)
  // [embB, embB+nER*4)      : e_ij
  // then mmax (n*4), ssum (n*4), g (n*4)   (contiguous -> one memset)
  char* w = (char*)d_ws;
  const size_t embB = (size_t)n * DD * sizeof(float);
  unsigned short* P = (unsigned short*)w;
  unsigned short* Q = P + (size_t)n * DD;
  float* U = (float*)w;   // overlaps P/Q; only used after k_eij is done
  char* w2 = w + embB;
  float* e_ij = (float*)w2;
  int* mmax = (int*)(w2 + (size_t)nER * 4);
  float* ssum = (float*)(w2 + (size_t)nER * 4 + (size_t)n * 4);
  float* g = (float*)(w2 + (size_t)nER * 4 + (size_t)n * 8);

  // zero mmax/ssum/g in one shot (int 0 == float 0.0, valid for the int-bits max)
  hipMemsetAsync(mmax, 0, (size_t)n * 12, stream);

  k_pq<<<(n + 63) / 64, 256, 0, stream>>>(emb, Wattn, battn, P, Q, n);
  k_eij<<<(nER * 16 + 255) / 256, 256, 0, stream>>>(P, Q, er_src, er_dst, w0w,
                                                    w0b, e_ij, mmax, nER);
  // U overlaps P/Q: zero it only after k_eij consumed them (stream-ordered)
  hipMemsetAsync(U, 0, embB, stream);
  k_agg<<<(nER * 16 + 255) / 256, 256, 0, stream>>>(emb, er_src, er_dst, e_ij,
                                                    mmax, ssum, U, nER);
  k_deg<<<(nEE + 255) / 256, 256, 0, stream>>>(ee_src, ee_w, g, nEE);
  k_out<<<(n + 31) / 32, 256, 0, stream>>>(emb, U, ssum, g, Wself, bself,
                                           Wneigh, bneigh, (float*)d_out, n);
}

// Round 2
// 558.770 us; speedup vs baseline: 7.1225x; 7.1225x over previous
//
#include <hip/hip_runtime.h>

#define DD 128

__device__ __forceinline__ float tanh_fast(float x) {
  float e = __expf(2.0f * x);
  return 1.0f - 2.0f / (e + 1.0f);
}

// f32 -> bf16 round-to-nearest-even
__device__ __forceinline__ unsigned short f2bf(float f) {
  unsigned u = __float_as_uint(f);
  u += 0x7FFFu + ((u >> 16) & 1u);
  return (unsigned short)(u >> 16);
}

__device__ __forceinline__ void fma4(float (&a)[4], float x, const float4 w) {
  a[0] = fmaf(x, w.x, a[0]);
  a[1] = fmaf(x, w.y, a[1]);
  a[2] = fmaf(x, w.z, a[2]);
  a[3] = fmaf(x, w.w, a[3]);
}

// K1: P[v] = emb[v] @ W_attn[0:128,:] + b_attn ; Q[v] = emb[v] @ W_attn[128:256,:]
extern "C" __global__ __launch_bounds__(256) void k_pq(
    const float* __restrict__ emb, const float* __restrict__ Wattn,
    const float* __restrict__ battn,
    unsigned short* __restrict__ P, unsigned short* __restrict__ Q, int n) {
  __shared__ float X[64][DD];
  const int tid = threadIdx.x;
  const int v0 = blockIdx.x * 64;
  const float4* emb4 = (const float4*)emb;
#pragma unroll
  for (int i = 0; i < 8; ++i) {
    int idx = tid + i * 256;
    int r = idx >> 5, c4 = idx & 31;
    int v = v0 + r;
    float4 val = make_float4(0.f, 0.f, 0.f, 0.f);
    if (v < n) val = emb4[(size_t)v * 32 + c4];
    *(float4*)&X[r][c4 * 4] = val;
  }
  __syncthreads();
  const int c = (tid & 31) * 4;
  const int r0 = (tid >> 5) * 8;
  float aP[8][4] = {};
  float aQ[8][4] = {};
  for (int k = 0; k < DD; ++k) {
    float4 wt = *(const float4*)&Wattn[k * DD + c];
    float4 wb = *(const float4*)&Wattn[(DD + k) * DD + c];
#pragma unroll
    for (int r = 0; r < 8; ++r) {
      float x = X[r0 + r][k];
      fma4(aP[r], x, wt);
      fma4(aQ[r], x, wb);
    }
  }
  float4 bb = *(const float4*)&battn[c];
#pragma unroll
  for (int r = 0; r < 8; ++r) {
    int v = v0 + r0 + r;
    if (v < n) {
      ushort4 sp, sq;
      sp.x = f2bf(aP[r][0] + bb.x);
      sp.y = f2bf(aP[r][1] + bb.y);
      sp.z = f2bf(aP[r][2] + bb.z);
      sp.w = f2bf(aP[r][3] + bb.w);
      sq.x = f2bf(aQ[r][0]);
      sq.y = f2bf(aQ[r][1]);
      sq.z = f2bf(aQ[r][2]);
      sq.w = f2bf(aQ[r][3]);
      *(ushort4*)&P[(size_t)v * DD + c] = sp;
      *(ushort4*)&Q[(size_t)v * DD + c] = sq;
    }
  }
}

// histogram of er_src
extern "C" __global__ __launch_bounds__(256) void k_hist(
    const int* __restrict__ src, int* __restrict__ count, int nE) {
  int e = blockIdx.x * 256 + threadIdx.x;
  if (e < nE) atomicAdd(&count[src[e]], 1);
}

// Blelloch exclusive scan, 512 elems/block, 256 threads; bsum[b] = chunk total
extern "C" __global__ __launch_bounds__(256) void k_scan(
    const int* __restrict__ in, int* __restrict__ outp,
    int* __restrict__ bsum, int n) {
  __shared__ int s[512];
  __shared__ int total;
  const int t = threadIdx.x;
  const int base = blockIdx.x * 512;
  for (int i = t; i < 512; i += 256) s[i] = (base + i < n) ? in[base + i] : 0;
  __syncthreads();
  for (int d = 1; d < 512; d <<= 1) {
    int stride = d * 2;
    int nidx = 512 / stride;
    if (t < nidx) {
      int idx = (t + 1) * stride - 1;
      s[idx] += s[idx - d];
    }
    __syncthreads();
  }
  if (t == 0) { total = s[511]; s[511] = 0; }
  __syncthreads();
  for (int d = 256; d >= 1; d >>= 1) {
    int stride = d * 2;
    int nidx = 512 / stride;
    if (t < nidx) {
      int idx = (t + 1) * stride - 1;
      int tmp = s[idx - d];
      s[idx - d] = s[idx];
      s[idx] += tmp;
    }
    __syncthreads();
  }
  for (int i = t; i < 512; i += 256)
    if (base + i < n) outp[base + i] = s[i];
  if (t == 0) bsum[blockIdx.x] = total;
}

extern "C" __global__ __launch_bounds__(256) void k_scan_add(
    int* __restrict__ off, const int* __restrict__ bofs, int n, int total) {
  int base = blockIdx.x * 512;
  int add = bofs[blockIdx.x];
  for (int i = threadIdx.x; i < 512; i += 256) {
    int idx = base + i;
    if (idx < n) off[idx] += add;
  }
  if (blockIdx.x == 0 && threadIdx.x == 0) off[n] = total;
}

// per ER edge: sv = tanh(P[dst]+Q[src]).w0 + w0_b ; scatter (sv, dst) into
// segment-sorted arrays via pos = off_mut[src]++. 16 lanes/edge.
extern "C" __global__ __launch_bounds__(256) void k_eij_scatter(
    const unsigned short* __restrict__ P, const unsigned short* __restrict__ Q,
    const int* __restrict__ src, const int* __restrict__ dstp,
    const float* __restrict__ w0w, const float* __restrict__ w0b,
    int* __restrict__ off_mut, float* __restrict__ eij_s,
    int* __restrict__ dst_s, int nE) {
  int t = blockIdx.x * 256 + threadIdx.x;
  int e = t >> 4;
  if (e >= nE) return;
  int lane = t & 15;
  int s = src[e], d = dstp[e];
  uint4 pv = *(const uint4*)(P + (size_t)d * DD + lane * 8);
  uint4 qv = *(const uint4*)(Q + (size_t)s * DD + lane * 8);
  float4 wa = *(const float4*)&w0w[lane * 8];
  float4 wbv = *(const float4*)&w0w[lane * 8 + 4];
  unsigned pw[4] = {pv.x, pv.y, pv.z, pv.w};
  unsigned qw[4] = {qv.x, qv.y, qv.z, qv.w};
  float wv[8] = {wa.x, wa.y, wa.z, wa.w, wbv.x, wbv.y, wbv.z, wbv.w};
  float acc = 0.f;
#pragma unroll
  for (int j = 0; j < 8; ++j) {
    unsigned up = (j & 1) ? (pw[j >> 1] & 0xFFFF0000u) : (pw[j >> 1] << 16);
    unsigned uq = (j & 1) ? (qw[j >> 1] & 0xFFFF0000u) : (qw[j >> 1] << 16);
    float x = __uint_as_float(up) + __uint_as_float(uq);
    acc = fmaf(tanh_fast(x), wv[j], acc);
  }
  acc += __shfl_xor(acc, 8);
  acc += __shfl_xor(acc, 4);
  acc += __shfl_xor(acc, 2);
  acc += __shfl_xor(acc, 1);
  if (lane == 0) {
    float sv = acc + w0b[0];
    int pos = atomicAdd(&off_mut[s], 1);
    eij_s[pos] = sv;
    dst_s[pos] = d;
  }
}

// node-centric aggregation: one wave per node. No atomics.
// U[v] = sum_e exp(eij - m) * emb[dst_e] ; ssum[v] = sum_e exp(eij - m)
extern "C" __global__ __launch_bounds__(256) void k_agg(
    const float* __restrict__ emb, const int* __restrict__ off,
    const int* __restrict__ dst_s, const float* __restrict__ eij_s,
    float* __restrict__ U, float* __restrict__ ssum, int n) {
  int v = (blockIdx.x * 256 + threadIdx.x) >> 6;
  int lane = threadIdx.x & 63;
  if (v >= n) return;
  int start = off[v], end = off[v + 1];
  // pass 1: segment max (clamped at 0, matching reference)
  float m = 0.0f;
  for (int i = start + lane; i < end; i += 64) m = fmaxf(m, eij_s[i]);
#pragma unroll
  for (int o = 32; o; o >>= 1) m = fmaxf(m, __shfl_xor(m, o));
  // pass 2: exp + weighted gather; 2 f32/lane accumulators
  float a0 = 0.f, a1 = 0.f, ssv = 0.f;
  const float2* emb2 = (const float2*)emb;
  for (int base = start; base < end; base += 64) {
    int i = base + lane;
    int dl = 0;
    float evl = 0.f;
    if (i < end) {
      dl = dst_s[i];
      evl = __expf(eij_s[i] - m);
    }
    int cnt = min(64, end - base);
    for (int j = 0; j < cnt; ++j) {
      int d = __shfl(dl, j);
      float ev = __shfl(evl, j);
      ssv += ev;
      float2 x = emb2[(size_t)d * 64 + lane];
      a0 = fmaf(ev, x.x, a0);
      a1 = fmaf(ev, x.y, a1);
    }
  }
  float2* U2 = (float2*)U;
  U2[(size_t)v * 64 + lane] = make_float2(a0, a1);
  if (lane == 0) ssum[v] = ssv;
}

// weighted out-degree over EE edges (gather and scatter are BOTH ee_src).
extern "C" __global__ __launch_bounds__(256) void k_deg(
    const int* __restrict__ src, const float* __restrict__ wgt,
    float* __restrict__ g, int nE) {
  int e = blockIdx.x * 256 + threadIdx.x;
  if (e < nE) unsafeAtomicAdd(&g[src[e]], wgt[e]);
}

// out = tanh( emb@W_self + b_self + M@W_neigh + (t+g)*b_neigh )
// M = U/(ssum+1e-9) + g*emb, t = ssum/(ssum+1e-9)
extern "C" __global__ __launch_bounds__(256) void k_out(
    const float* __restrict__ emb, const float* __restrict__ U,
    const float* __restrict__ ssum, const float* __restrict__ g,
    const float* __restrict__ Wself, const float* __restrict__ bself,
    const float* __restrict__ Wneigh, const float* __restrict__ bneigh,
    float* __restrict__ out, int n) {
  __shared__ float X1[32][DD];
  __shared__ float X2[32][DD];
  const int tid = threadIdx.x;
  const int v0 = blockIdx.x * 32;
  const float4* emb4 = (const float4*)emb;
  const float4* U4 = (const float4*)U;
#pragma unroll
  for (int i = 0; i < 4; ++i) {
    int idx = tid + i * 256;
    int r = idx >> 5, c4 = idx & 31;
    int v = v0 + r;
    float4 x = make_float4(0.f, 0.f, 0.f, 0.f);
    float4 mm = x;
    if (v < n) {
      x = emb4[(size_t)v * 32 + c4];
      float4 u = U4[(size_t)v * 32 + c4];
      float sv = ssum[v];
      float gv = g[v];
      float inv = 1.0f / (sv + 1e-9f);
      mm.x = fmaf(gv, x.x, u.x * inv);
      mm.y = fmaf(gv, x.y, u.y * inv);
      mm.z = fmaf(gv, x.z, u.z * inv);
      mm.w = fmaf(gv, x.w, u.w * inv);
    }
    *(float4*)&X1[r][c4 * 4] = x;
    *(float4*)&X2[r][c4 * 4] = mm;
  }
  __syncthreads();
  const int c = (tid & 31) * 4;
  const int r0 = (tid >> 5) * 4;
  float acc[4][4] = {};
  for (int k = 0; k < DD; ++k) {
    float4 ws = *(const float4*)&Wself[k * DD + c];
    float4 wn = *(const float4*)&Wneigh[k * DD + c];
#pragma unroll
    for (int r = 0; r < 4; ++r) {
      float x1 = X1[r0 + r][k];
      float x2 = X2[r0 + r][k];
      fma4(acc[r], x1, ws);
      fma4(acc[r], x2, wn);
    }
  }
  float4 bs = *(const float4*)&bself[c];
  float4 bn = *(const float4*)&bneigh[c];
#pragma unroll
  for (int r = 0; r < 4; ++r) {
    int v = v0 + r0 + r;
    if (v < n) {
      float sv = ssum[v];
      float gv = g[v];
      float tg = sv / (sv + 1e-9f) + gv;
      float4 y;
      y.x = tanh_fast(acc[r][0] + bs.x + tg * bn.x);
      y.y = tanh_fast(acc[r][1] + bs.y + tg * bn.y);
      y.z = tanh_fast(acc[r][2] + bs.z + tg * bn.z);
      y.w = tanh_fast(acc[r][3] + bs.w + tg * bn.w);
      *(float4*)&out[(size_t)v * DD + c] = y;
    }
  }
}

extern "C" void kernel_launch(void* const* d_in, const int* in_sizes, int n_in,
                              void* d_out, int out_size, void* d_ws, size_t ws_size,
                              hipStream_t stream) {
  const float* emb = (const float*)d_in[0];
  const int* er_src = (const int*)d_in[1];
  const int* er_dst = (const int*)d_in[2];
  const int* ee_src = (const int*)d_in[3];
  const float* ee_w = (const float*)d_in[5];
  const float* Wattn = (const float*)d_in[6];
  const float* battn = (const float*)d_in[7];
  const float* w0w = (const float*)d_in[8];
  const float* w0b = (const float*)d_in[9];
  const float* Wself = (const float*)d_in[10];
  const float* bself = (const float*)d_in[11];
  const float* Wneigh = (const float*)d_in[12];
  const float* bneigh = (const float*)d_in[13];
  const int n = in_sizes[0] / DD;
  const int nER = in_sizes[1];
  const int nEE = in_sizes[3];

  // workspace layout
  char* w = (char*)d_ws;
  size_t o = 0;
  float* U = (float*)w;                       // n*128 f32, overlaps P/Q
  unsigned short* P = (unsigned short*)w;     // n*128 bf16
  unsigned short* Q = P + (size_t)n * DD;     // n*128 bf16
  o += (size_t)n * DD * 4;
  int* dst_s = (int*)(w + o);  o += (size_t)nER * 4;
  float* eij_s = (float*)(w + o); o += (size_t)nER * 4;
  int* count = (int*)(w + o);  o += (size_t)n * 4;
  float* g = (float*)(w + o);  o += (size_t)n * 4;   // adjacent to count
  int* off = (int*)(w + o);    o += (size_t)(n + 1) * 4;
  int* off_mut = (int*)(w + o); o += (size_t)n * 4;
  float* ssum = (float*)(w + o); o += (size_t)n * 4;
  int* bsum = (int*)(w + o);   o += 4096;            // chunk partials
  int* dummy = (int*)(w + o);  o += 64;

  const int nb = (n + 511) / 512;

  hipMemsetAsync(count, 0, (size_t)n * 8, stream);   // count + g

  k_pq<<<(n + 63) / 64, 256, 0, stream>>>(emb, Wattn, battn, P, Q, n);
  k_hist<<<(nER + 255) / 256, 256, 0, stream>>>(er_src, count, nER);
  k_scan<<<nb, 256, 0, stream>>>(count, off, bsum, n);
  k_scan<<<1, 256, 0, stream>>>(bsum, bsum, dummy, nb);
  k_scan_add<<<nb, 256, 0, stream>>>(off, bsum, n, nER);
  hipMemcpyAsync(off_mut, off, (size_t)n * 4, hipMemcpyDeviceToDevice, stream);
  k_eij_scatter<<<(nER * 16 + 255) / 256, 256, 0, stream>>>(
      P, Q, er_src, er_dst, w0w, w0b, off_mut, eij_s, dst_s, nER);
  k_agg<<<(n + 3) / 4, 256, 0, stream>>>(emb, off, dst_s, eij_s, U, ssum, n);
  k_deg<<<(nEE + 255) / 256, 256, 0, stream>>>(ee_src, ee_w, g, nEE);
  k_out<<<(n + 31) / 32, 256, 0, stream>>>(emb, U, ssum, g, Wself, bself,
                                           Wneigh, bneigh, (float*)d_out, n);
}

// Round 4
// 402.202 us; speedup vs baseline: 9.8951x; 1.3893x over previous
//
#include <hip/hip_runtime.h>

#define DD 128

typedef short s16x8 __attribute__((ext_vector_type(8)));
typedef float f32x4 __attribute__((ext_vector_type(4)));

__device__ __forceinline__ float tanh_fast(float x) {
  float e = __expf(2.0f * x);
  return 1.0f - 2.0f / (e + 1.0f);
}

// f32 -> bf16 round-to-nearest-even
__device__ __forceinline__ unsigned short f2bf(float f) {
  unsigned u = __float_as_uint(f);
  u += 0x7FFFu + ((u >> 16) & 1u);
  return (unsigned short)(u >> 16);
}

__device__ __forceinline__ float bf2f(unsigned short u) {
  return __uint_as_float(((unsigned)u) << 16);
}

// emb f32 -> bf16 (8 elems/thread)
extern "C" __global__ __launch_bounds__(256) void k_tobf(
    const float* __restrict__ emb, unsigned short* __restrict__ ebf, int total8) {
  int i = blockIdx.x * 256 + threadIdx.x;
  if (i >= total8) return;
  const float4* e4 = (const float4*)emb;
  float4 x = e4[(size_t)i * 2];
  float4 y = e4[(size_t)i * 2 + 1];
  uint4 o;
  o.x = (unsigned)f2bf(x.x) | ((unsigned)f2bf(x.y) << 16);
  o.y = (unsigned)f2bf(x.z) | ((unsigned)f2bf(x.w) << 16);
  o.z = (unsigned)f2bf(y.x) | ((unsigned)f2bf(y.y) << 16);
  o.w = (unsigned)f2bf(y.z) | ((unsigned)f2bf(y.w) << 16);
  *(uint4*)(ebf + (size_t)i * 8) = o;
}

// pack Wcat = [Wattn[0:128] | Wattn[128:256]] (128k x 256c) into B-frag layout:
// WB[((ct*4+ks)*64+lane)*8 + j] = Wcat[ks*32+(lane>>4)*8+j][ct*16+(lane&15)]
extern "C" __global__ __launch_bounds__(256) void k_packw1(
    const float* __restrict__ Wattn, unsigned short* __restrict__ WB) {
  int t = blockIdx.x * 256 + threadIdx.x;  // 0..4095
  int lane = t & 63;
  int cks = t >> 6;           // ct*4+ks
  int ks = cks & 3, ct = cks >> 2;
  int c = ct * 16 + (lane & 15);
  int kb = ks * 32 + ((lane >> 4) << 3);
  const float* srcp = (c < DD) ? (Wattn + (size_t)kb * DD + c)
                               : (Wattn + (size_t)(DD + kb) * DD + (c - DD));
  unsigned short* dst = WB + (size_t)t * 8;
#pragma unroll
  for (int j = 0; j < 8; ++j) dst[j] = f2bf(srcp[(size_t)j * DD]);
}

// pack Wcat2 = [Wself ; Wneigh] (256k x 128c) into hi/lo B-frag layout (8 ct, 8 ks)
extern "C" __global__ __launch_bounds__(256) void k_packw2(
    const float* __restrict__ Wself, const float* __restrict__ Wneigh,
    unsigned short* __restrict__ WBh, unsigned short* __restrict__ WBl) {
  int t = blockIdx.x * 256 + threadIdx.x;  // 0..4095
  int lane = t & 63;
  int cks = t >> 6;           // ct*8+ks
  int ks = cks & 7, ct = cks >> 3;
  int c = ct * 16 + (lane & 15);
  int k0 = ks * 32 + ((lane >> 4) << 3);
#pragma unroll
  for (int j = 0; j < 8; ++j) {
    int k = k0 + j;
    float v = (k < DD) ? Wself[(size_t)k * DD + c] : Wneigh[(size_t)(k - DD) * DD + c];
    unsigned short h = f2bf(v);
    float r = v - bf2f(h);
    WBh[(size_t)t * 8 + j] = h;
    WBl[(size_t)t * 8 + j] = f2bf(r);
  }
}

// PQ[v][c] (c<128: P=emb@Wattn_r+battn, c>=128: Q=emb@Wattn_h), bf16.
// 64 rows/block, 4 waves, 16 col-tiles x 4 ksteps of mfma 16x16x32 bf16.
extern "C" __global__ __launch_bounds__(256) void k_pq_mfma(
    const unsigned short* __restrict__ ebf, const unsigned short* __restrict__ WB,
    const float* __restrict__ battn, unsigned short* __restrict__ PQ, int n) {
  const int wave = threadIdx.x >> 6, lane = threadIdx.x & 63;
  const int v0 = blockIdx.x * 64 + wave * 16;
  const int row = v0 + (lane & 15);
  const int kb = (lane >> 4) << 3;
  const bool rok = row < n;
  const s16x8 zf = {0, 0, 0, 0, 0, 0, 0, 0};
  s16x8 a[4];
#pragma unroll
  for (int ks = 0; ks < 4; ++ks)
    a[ks] = rok ? *(const s16x8*)(ebf + (size_t)row * DD + ks * 32 + kb) : zf;
  f32x4 acc[16];
#pragma unroll
  for (int ct = 0; ct < 16; ++ct) acc[ct] = (f32x4)(0.f);
  const s16x8* wb = (const s16x8*)WB;
#pragma unroll
  for (int ct = 0; ct < 16; ++ct) {
#pragma unroll
    for (int ks = 0; ks < 4; ++ks) {
      s16x8 b = wb[(ct * 4 + ks) * 64 + lane];
      acc[ct] = __builtin_amdgcn_mfma_f32_16x16x32_bf16(a[ks], b, acc[ct], 0, 0, 0);
    }
  }
  const int r0 = (lane >> 4) << 2;
  const int col0 = lane & 15;
#pragma unroll
  for (int ct = 0; ct < 16; ++ct) {
    int c = ct * 16 + col0;
    float bias = (c < DD) ? battn[c] : 0.f;
#pragma unroll
    for (int r = 0; r < 4; ++r) {
      int v = v0 + r0 + r;
      if (v < n) PQ[(size_t)v * 256 + c] = f2bf(acc[ct][r] + bias);
    }
  }
}

// histogram of er_src
extern "C" __global__ __launch_bounds__(256) void k_hist(
    const int* __restrict__ src, int* __restrict__ count, int nE) {
  int e = blockIdx.x * 256 + threadIdx.x;
  if (e < nE) atomicAdd(&count[src[e]], 1);
}

// Blelloch exclusive scan, 512 elems/block; bsum[b] = chunk total
extern "C" __global__ __launch_bounds__(256) void k_scan(
    const int* __restrict__ in, int* __restrict__ outp,
    int* __restrict__ bsum, int n) {
  __shared__ int s[512];
  __shared__ int total;
  const int t = threadIdx.x;
  const int base = blockIdx.x * 512;
  for (int i = t; i < 512; i += 256) s[i] = (base + i < n) ? in[base + i] : 0;
  __syncthreads();
  for (int d = 1; d < 512; d <<= 1) {
    int stride = d * 2;
    int nidx = 512 / stride;
    if (t < nidx) {
      int idx = (t + 1) * stride - 1;
      s[idx] += s[idx - d];
    }
    __syncthreads();
  }
  if (t == 0) { total = s[511]; s[511] = 0; }
  __syncthreads();
  for (int d = 256; d >= 1; d >>= 1) {
    int stride = d * 2;
    int nidx = 512 / stride;
    if (t < nidx) {
      int idx = (t + 1) * stride - 1;
      int tmp = s[idx - d];
      s[idx - d] = s[idx];
      s[idx] += tmp;
    }
    __syncthreads();
  }
  for (int i = t; i < 512; i += 256)
    if (base + i < n) outp[base + i] = s[i];
  if (t == 0) bsum[blockIdx.x] = total;
}

extern "C" __global__ __launch_bounds__(256) void k_scan_add(
    int* __restrict__ off, const int* __restrict__ bofs, int n, int total) {
  int base = blockIdx.x * 512;
  int add = bofs[blockIdx.x];
  for (int i = threadIdx.x; i < 512; i += 256) {
    int idx = base + i;
    if (idx < n) off[idx] += add;
  }
  if (blockIdx.x == 0 && threadIdx.x == 0) off[n] = total;
}

// per ER edge: sv = tanh(P[dst]+Q[src]).w0 + w0_b ; scatter (sv, dst) via
// pos = off_mut[src]++. 16 lanes/edge. PQ layout: [v][0:128]=P, [v][128:256]=Q.
extern "C" __global__ __launch_bounds__(256) void k_eij_scatter(
    const unsigned short* __restrict__ PQ,
    const int* __restrict__ src, const int* __restrict__ dstp,
    const float* __restrict__ w0w, const float* __restrict__ w0b,
    int* __restrict__ off_mut, float* __restrict__ eij_s,
    int* __restrict__ dst_s, int nE) {
  int t = blockIdx.x * 256 + threadIdx.x;
  int e = t >> 4;
  if (e >= nE) return;
  int lane = t & 15;
  int s = src[e], d = dstp[e];
  uint4 pv = *(const uint4*)(PQ + (size_t)d * 256 + lane * 8);
  uint4 qv = *(const uint4*)(PQ + (size_t)s * 256 + DD + lane * 8);
  float4 wa = *(const float4*)&w0w[lane * 8];
  float4 wbv = *(const float4*)&w0w[lane * 8 + 4];
  unsigned pw[4] = {pv.x, pv.y, pv.z, pv.w};
  unsigned qw[4] = {qv.x, qv.y, qv.z, qv.w};
  float wv[8] = {wa.x, wa.y, wa.z, wa.w, wbv.x, wbv.y, wbv.z, wbv.w};
  float acc = 0.f;
#pragma unroll
  for (int j = 0; j < 8; ++j) {
    unsigned up = (j & 1) ? (pw[j >> 1] & 0xFFFF0000u) : (pw[j >> 1] << 16);
    unsigned uq = (j & 1) ? (qw[j >> 1] & 0xFFFF0000u) : (qw[j >> 1] << 16);
    float x = __uint_as_float(up) + __uint_as_float(uq);
    acc = fmaf(tanh_fast(x), wv[j], acc);
  }
  acc += __shfl_xor(acc, 8);
  acc += __shfl_xor(acc, 4);
  acc += __shfl_xor(acc, 2);
  acc += __shfl_xor(acc, 1);
  if (lane == 0) {
    float sv = acc + w0b[0];
    int pos = atomicAdd(&off_mut[s], 1);
    eij_s[pos] = sv;
    dst_s[pos] = d;
  }
}

// node-centric aggregation: one wave per node, gathers bf16 emb. No atomics.
extern "C" __global__ __launch_bounds__(256) void k_agg(
    const unsigned short* __restrict__ ebf, const int* __restrict__ off,
    const int* __restrict__ dst_s, const float* __restrict__ eij_s,
    float* __restrict__ U, float* __restrict__ ssum, int n) {
  int v = (blockIdx.x * 256 + threadIdx.x) >> 6;
  int lane = threadIdx.x & 63;
  if (v >= n) return;
  int start = off[v], end = off[v + 1];
  float m = 0.0f;
  for (int i = start + lane; i < end; i += 64) m = fmaxf(m, eij_s[i]);
#pragma unroll
  for (int o = 32; o; o >>= 1) m = fmaxf(m, __shfl_xor(m, o));
  float a0 = 0.f, a1 = 0.f, ssv = 0.f;
  for (int base = start; base < end; base += 64) {
    int i = base + lane;
    int dl = 0;
    float evl = 0.f;
    if (i < end) {
      dl = dst_s[i];
      evl = __expf(eij_s[i] - m);
    }
    int cnt = min(64, end - base);
    for (int j = 0; j < cnt; ++j) {
      int d = __shfl(dl, j);
      float ev = __shfl(evl, j);
      ssv += ev;
      unsigned x = *(const unsigned*)(ebf + (size_t)d * DD + lane * 2);
      a0 = fmaf(ev, bf2f((unsigned short)(x & 0xFFFFu)), a0);
      a1 = fmaf(ev, bf2f((unsigned short)(x >> 16)), a1);
    }
  }
  float2* U2 = (float2*)U;
  U2[(size_t)v * 64 + lane] = make_float2(a0, a1);
  if (lane == 0) ssum[v] = ssv;
}

// weighted out-degree over EE edges
extern "C" __global__ __launch_bounds__(256) void k_deg(
    const int* __restrict__ src, const float* __restrict__ wgt,
    float* __restrict__ g, int nE) {
  int e = blockIdx.x * 256 + threadIdx.x;
  if (e < nE) unsafeAtomicAdd(&g[src[e]], wgt[e]);
}

// out = tanh([emb | M] @ [Wself;Wneigh] + bself + tg*bneigh), M = U*inv + g*emb.
// Split-precision: A and B as bf16 hi/lo; acc = AhBh + AlBh + AhBl.
// 64 rows/block, 4 waves, 8 col-tiles x 8 ksteps.
extern "C" __global__ __launch_bounds__(256) void k_out_mfma(
    const float* __restrict__ emb, const float* __restrict__ U,
    const float* __restrict__ ssum, const float* __restrict__ g,
    const unsigned short* __restrict__ WBh, const unsigned short* __restrict__ WBl,
    const float* __restrict__ bself, const float* __restrict__ bneigh,
    float* __restrict__ out, int n) {
  const int wave = threadIdx.x >> 6, lane = threadIdx.x & 63;
  const int v0 = blockIdx.x * 64 + wave * 16;
  const int row = v0 + (lane & 15);
  const int kb = (lane >> 4) << 3;
  const bool rok = row < n;
  float inv = 0.f, gv = 0.f;
  if (rok) {
    float sv = ssum[row];
    inv = 1.f / (sv + 1e-9f);
    gv = g[row];
  }
  s16x8 ah[8], al[8];
#pragma unroll
  for (int ks = 0; ks < 8; ++ks) {
    int k0 = (ks & 3) * 32 + kb;
    float x[8] = {0.f, 0.f, 0.f, 0.f, 0.f, 0.f, 0.f, 0.f};
    if (rok) {
      float4 ea = *(const float4*)(emb + (size_t)row * DD + k0);
      float4 eb = *(const float4*)(emb + (size_t)row * DD + k0 + 4);
      x[0] = ea.x; x[1] = ea.y; x[2] = ea.z; x[3] = ea.w;
      x[4] = eb.x; x[5] = eb.y; x[6] = eb.z; x[7] = eb.w;
      if (ks >= 4) {
        float4 ua = *(const float4*)(U + (size_t)row * DD + k0);
        float4 ub = *(const float4*)(U + (size_t)row * DD + k0 + 4);
        x[0] = fmaf(gv, x[0], ua.x * inv);
        x[1] = fmaf(gv, x[1], ua.y * inv);
        x[2] = fmaf(gv, x[2], ua.z * inv);
        x[3] = fmaf(gv, x[3], ua.w * inv);
        x[4] = fmaf(gv, x[4], ub.x * inv);
        x[5] = fmaf(gv, x[5], ub.y * inv);
        x[6] = fmaf(gv, x[6], ub.z * inv);
        x[7] = fmaf(gv, x[7], ub.w * inv);
      }
    }
    unsigned short hh[8], ll[8];
#pragma unroll
    for (int j = 0; j < 8; ++j) {
      unsigned short h = f2bf(x[j]);
      hh[j] = h;
      ll[j] = f2bf(x[j] - bf2f(h));
    }
    ah[ks] = *(const s16x8*)hh;
    al[ks] = *(const s16x8*)ll;
  }
  f32x4 acc[8];
#pragma unroll
  for (int ct = 0; ct < 8; ++ct) acc[ct] = (f32x4)(0.f);
  const s16x8* wbh = (const s16x8*)WBh;
  const s16x8* wbl = (const s16x8*)WBl;
#pragma unroll
  for (int ct = 0; ct < 8; ++ct) {
#pragma unroll
    for (int ks = 0; ks < 8; ++ks) {
      s16x8 bh = wbh[(ct * 8 + ks) * 64 + lane];
      s16x8 bl = wbl[(ct * 8 + ks) * 64 + lane];
      acc[ct] = __builtin_amdgcn_mfma_f32_16x16x32_bf16(ah[ks], bh, acc[ct], 0, 0, 0);
      acc[ct] = __builtin_amdgcn_mfma_f32_16x16x32_bf16(al[ks], bh, acc[ct], 0, 0, 0);
      acc[ct] = __builtin_amdgcn_mfma_f32_16x16x32_bf16(ah[ks], bl, acc[ct], 0, 0, 0);
    }
  }
  const int r0 = (lane >> 4) << 2;
  const int col0 = lane & 15;
  float tgr[4];
#pragma unroll
  for (int r = 0; r < 4; ++r) {
    int v = v0 + r0 + r;
    float tg = 0.f;
    if (v < n) {
      float sv = ssum[v];
      tg = sv / (sv + 1e-9f) + g[v];
    }
    tgr[r] = tg;
  }
#pragma unroll
  for (int ct = 0; ct < 8; ++ct) {
    int c = ct * 16 + col0;
    float bs = bself[c], bn = bneigh[c];
#pragma unroll
    for (int r = 0; r < 4; ++r) {
      int v = v0 + r0 + r;
      if (v < n) out[(size_t)v * DD + c] = tanh_fast(acc[ct][r] + bs + tgr[r] * bn);
    }
  }
}

static inline size_t al16(size_t x) { return (x + 15) & ~(size_t)15; }

extern "C" void kernel_launch(void* const* d_in, const int* in_sizes, int n_in,
                              void* d_out, int out_size, void* d_ws, size_t ws_size,
                              hipStream_t stream) {
  const float* emb = (const float*)d_in[0];
  const int* er_src = (const int*)d_in[1];
  const int* er_dst = (const int*)d_in[2];
  const int* ee_src = (const int*)d_in[3];
  const float* ee_w = (const float*)d_in[5];
  const float* Wattn = (const float*)d_in[6];
  const float* battn = (const float*)d_in[7];
  const float* w0w = (const float*)d_in[8];
  const float* w0b = (const float*)d_in[9];
  const float* Wself = (const float*)d_in[10];
  const float* bself = (const float*)d_in[11];
  const float* Wneigh = (const float*)d_in[12];
  const float* bneigh = (const float*)d_in[13];
  const int n = in_sizes[0] / DD;
  const int nER = in_sizes[1];
  const int nEE = in_sizes[3];

  // workspace layout (16B-aligned slices)
  char* w = (char*)d_ws;
  size_t o = 0;
  unsigned short* ebf = (unsigned short*)(w + o); o += al16((size_t)n * DD * 2);
  unsigned short* PQ  = (unsigned short*)(w + o);
  float* U = (float*)(w + o);                     o += al16((size_t)n * 256 * 2); // PQ/U alias
  int* dst_s = (int*)(w + o);   o += al16((size_t)nER * 4);
  float* eij_s = (float*)(w + o); o += al16((size_t)nER * 4);
  int* count = (int*)(w + o);   o += al16((size_t)n * 4);
  float* g = (float*)(w + o);   o += al16((size_t)n * 4);   // adjacent to count
  int* off = (int*)(w + o);     o += al16((size_t)(n + 4) * 4);
  int* off_mut = (int*)(w + o); o += al16((size_t)n * 4);
  float* ssum = (float*)(w + o); o += al16((size_t)n * 4);
  unsigned short* WB = (unsigned short*)(w + o);   o += 65536;
  unsigned short* WB2h = (unsigned short*)(w + o); o += 65536;
  unsigned short* WB2l = (unsigned short*)(w + o); o += 65536;
  int* bsum = (int*)(w + o);    o += 4096;
  int* dummy = (int*)(w + o);   o += 64;

  const int nb = (n + 511) / 512;
  const int total8 = n * DD / 8;

  hipMemsetAsync(count, 0, (size_t)n * 8, stream);  // count + g

  k_tobf<<<(total8 + 255) / 256, 256, 0, stream>>>(emb, ebf, total8);
  k_packw1<<<16, 256, 0, stream>>>(Wattn, WB);
  k_packw2<<<16, 256, 0, stream>>>(Wself, Wneigh, WB2h, WB2l);
  k_pq_mfma<<<(n + 63) / 64, 256, 0, stream>>>(ebf, WB, battn, PQ, n);
  k_hist<<<(nER + 255) / 256, 256, 0, stream>>>(er_src, count, nER);
  k_scan<<<nb, 256, 0, stream>>>(count, off, bsum, n);
  k_scan<<<1, 256, 0, stream>>>(bsum, bsum, dummy, nb);
  k_scan_add<<<nb, 256, 0, stream>>>(off, bsum, n, nER);
  hipMemcpyAsync(off_mut, off, (size_t)n * 4, hipMemcpyDeviceToDevice, stream);
  k_eij_scatter<<<(nER * 16 + 255) / 256, 256, 0, stream>>>(
      PQ, er_src, er_dst, w0w, w0b, off_mut, eij_s, dst_s, nER);
  k_agg<<<(n + 3) / 4, 256, 0, stream>>>(ebf, off, dst_s, eij_s, U, ssum, n);
  k_deg<<<(nEE + 255) / 256, 256, 0, stream>>>(ee_src, ee_w, g, nEE);
  k_out_mfma<<<(n + 63) / 64, 256, 0, stream>>>(emb, U, ssum, g, WB2h, WB2l,
                                                bself, bneigh, (float*)d_out, n);
}